// Round 15
// baseline (34.047 us; speedup 1.0000x reference)
//
#include <hip/hip_runtime.h>

#define T_LEN  512
#define K_LEN  64
#define NFILT  32
#define NBATCH 64
#define XOFS2  64
#define XS2_SZ 384               // max idx = 64 + 319 = 383
#define SQRT_LOG2E 1.2011224087864498f
#define LN2        0.6931471805599453f

typedef __attribute__((ext_vector_type(2))) float f32x2;

// result[lane] = src[lane-1], lane0 -> 0 (DPP wave_shr:1, bound_ctrl=1)
static __device__ __forceinline__ float wave_shr1(float x) {
    int r = __builtin_amdgcn_update_dpp(0, __builtin_bit_cast(int, x),
                                        0x138, 0xF, 0xF, true);
    return __builtin_bit_cast(float, r);
}

static __device__ __forceinline__ f32x2 wave_shr1_x2(f32x2 v) {
    f32x2 r;
    r.x = wave_shr1(v.x);
    r.y = wave_shr1(v.y);
    return r;
}

template <int N>
static __device__ __forceinline__ float row_ror(float x) {
    int r = __builtin_amdgcn_update_dpp(0, __builtin_bit_cast(int, x),
                                        0x120 + N, 0xF, 0xF, true);
    return __builtin_bit_cast(float, r);
}

static __device__ __forceinline__ float exp2_fast(float x) {
#if __has_builtin(__builtin_amdgcn_exp2f)
    return __builtin_amdgcn_exp2f(x);
#else
    return exp2f(x);
#endif
}

// exact fp32 band interval for original column jj = j/63 (reference predicate)
static __device__ __forceinline__ void band_iv(float jj, int& lo, int& hi) {
    int a0 = 0, b0 = T_LEN - 1;
    while (a0 < b0) { int m = (a0 + b0) >> 1;
        if ((float)m / 511.0f - jj >= -0.2f) b0 = m; else a0 = m + 1; }
    lo = a0;
    a0 = 0; b0 = T_LEN - 1;
    while (a0 < b0) { int m = (a0 + b0 + 1) >> 1;
        if ((float)m / 511.0f - jj <= 0.2f) a0 = m; else b0 = m - 1; }
    hi = a0;
}

// BIDIRECTIONAL linear-domain soft-DTW: one problem per wave, 2048 waves.
// Every monotone path crosses row 255->256 exactly once (down or diag):
//   Z = sum_j Zf(255,j) * (Zb(256,j) + Zb(256,j+1))
// .x chain = forward DP rows 0..255 (columns = lanes);
// .y chain = backward DP rows 511..256 == forward DP on reversed x & protos.
// Both are 319-step anti-diagonal sweeps (vs 575 single-direction) and run
// packed (v_pk_*). Row-255 values are captured in-flight; epilogue combines.
__global__ __launch_bounds__(256) void dtw_kernel(const float* __restrict__ x,
                                                  const float* __restrict__ protos,
                                                  float* __restrict__ out) {
    __shared__ f32x2 xs2[XS2_SZ];
    const int tid  = threadIdx.x;
    const int lane = tid & 63;
    const int wid  = tid >> 6;
    const int idx  = (blockIdx.x << 2) | wid;       // 0..2047
    const int b    = idx >> 5;                      // same b for all 4 waves
    const int f    = idx & 31;

    // stage {x[i], x[511-i]} * sqrt(log2 e), zero-padded
    for (int t0 = tid; t0 < XS2_SZ; t0 += 256) {
        int i = t0 - XOFS2;
        f32x2 v;
        bool ok = (i >= 0 && i < T_LEN);
        v.x = ok ? x[b * T_LEN + i] * SQRT_LOG2E : 0.0f;
        v.y = ok ? x[b * T_LEN + (T_LEN - 1) - i] * SQRT_LOG2E : 0.0f;
        xs2[t0] = v;
    }
    __syncthreads();

    const int jF = lane, jB = 63 - lane;            // original columns
    f32x2 pn2;
    pn2.x = -protos[f * K_LEN + jF] * SQRT_LOG2E;
    pn2.y = -protos[f * K_LEN + jB] * SQRT_LOG2E;

    int iloF, ihiF, iloB, ihiB;
    band_iv((float)jF / 63.0f, iloF, ihiF);
    band_iv((float)jB / 63.0f, iloB, ihiB);

    // fwd: original rows [iloF, min(ihiF,255)]
    const int loF = iloF, hiF = (ihiF < 255) ? ihiF : 255;
    // bwd: original rows [max(iloB,256), ihiB] -> reversed i_r = 511 - i
    const int loBo = (iloB > 256) ? iloB : 256;
    const int loB  = (T_LEN - 1) - ihiB;
    const int hiB  = (T_LEN - 1) - loBo;

    unsigned tF, rangeF, tB, rangeB;
    if (loF > hiF) { tF = 0x80000000u; rangeF = 0u; }
    else { tF = (unsigned)(-(lane + loF)); rangeF = (unsigned)(hiF - loF); }
    if (loB > hiB) { tB = 0x80000000u; rangeB = 0u; }
    else { tB = (unsigned)(-(lane + loB)); rangeB = (unsigned)(hiB - loB); }

    f32x2 prev2; prev2.x = 0.0f; prev2.y = 0.0f;
    f32x2 cap2;  cap2.x  = 0.0f; cap2.y  = 0.0f;
    const float d0 = (lane == 0) ? 1.0f : 0.0f;     // Z(-1,-1) = 1 (both)
    f32x2 dgp2; dgp2.x = d0; dgp2.y = d0;
    int S2x = 0, S2y = 0;
    const int dcap = 255 + lane;                    // capture step (both chains)

    const f32x2* __restrict__ xp = &xs2[XOFS2 - lane];

    f32x2 A[32], Bv[32];
#pragma unroll
    for (int k = 0; k < 32; ++k) A[k] = xp[k];
    __builtin_amdgcn_sched_barrier(0);

#define STEP(XV, DCONST, CAPF) do {                           \
        f32x2 xv2_ = (XV);                                    \
        float selF_ = (tF <= rangeF) ? 0.0f : -3.0e38f; ++tF; \
        float selB_ = (tB <= rangeB) ? 0.0f : -3.0e38f; ++tB; \
        float dF_ = xv2_.x + pn2.x;                           \
        float dB_ = xv2_.y + pn2.y;                           \
        f32x2 w2_;                                            \
        w2_.x = exp2_fast(__builtin_fmaf(dF_, -dF_, selF_));  \
        w2_.y = exp2_fast(__builtin_fmaf(dB_, -dB_, selB_));  \
        f32x2 l2_ = wave_shr1_x2(prev2);                      \
        f32x2 a2_ = prev2 + dgp2;                             \
        f32x2 s2_ = a2_ + l2_;                                \
        dgp2  = l2_;                                          \
        prev2 = s2_ * w2_;                                    \
        if (CAPF) {                                           \
            bool c_ = (dcap == (DCONST));                     \
            cap2.x = c_ ? prev2.x : cap2.x;                   \
            cap2.y = c_ ? prev2.y : cap2.y;                   \
        }                                                     \
    } while (0)

    // wave-uniform power-of-2 renorm to max ~2^30 (Me=284-e), cadence 32
#define RENORM() do {                                                        \
        float MA_, MB_;                                                      \
        {                                                                    \
            float m_ = prev2.x;                                              \
            m_ = fmaxf(m_, row_ror<8>(m_));                                  \
            m_ = fmaxf(m_, row_ror<4>(m_));                                  \
            m_ = fmaxf(m_, row_ror<2>(m_));                                  \
            m_ = fmaxf(m_, row_ror<1>(m_));                                  \
            int mi_ = __builtin_bit_cast(int, m_);                           \
            unsigned r0_ = (unsigned)__builtin_amdgcn_readlane(mi_, 0);      \
            unsigned r1_ = (unsigned)__builtin_amdgcn_readlane(mi_, 16);     \
            unsigned r2_ = (unsigned)__builtin_amdgcn_readlane(mi_, 32);     \
            unsigned r3_ = (unsigned)__builtin_amdgcn_readlane(mi_, 48);     \
            unsigned ra_ = r0_ > r1_ ? r0_ : r1_;                            \
            unsigned rb_ = r2_ > r3_ ? r2_ : r3_;                            \
            unsigned mx_ = ra_ > rb_ ? ra_ : rb_;                            \
            int e_  = (int)((mx_ >> 23) & 0xFF);                             \
            int Me_ = 284 - e_;                                              \
            Me_ = Me_ < 1 ? 1 : (Me_ > 254 ? 254 : Me_);                     \
            MA_ = __builtin_bit_cast(float, Me_ << 23);                      \
            S2x += Me_ - 127;                                                \
        }                                                                    \
        {                                                                    \
            float m_ = prev2.y;                                              \
            m_ = fmaxf(m_, row_ror<8>(m_));                                  \
            m_ = fmaxf(m_, row_ror<4>(m_));                                  \
            m_ = fmaxf(m_, row_ror<2>(m_));                                  \
            m_ = fmaxf(m_, row_ror<1>(m_));                                  \
            int mi_ = __builtin_bit_cast(int, m_);                           \
            unsigned r0_ = (unsigned)__builtin_amdgcn_readlane(mi_, 0);      \
            unsigned r1_ = (unsigned)__builtin_amdgcn_readlane(mi_, 16);     \
            unsigned r2_ = (unsigned)__builtin_amdgcn_readlane(mi_, 32);     \
            unsigned r3_ = (unsigned)__builtin_amdgcn_readlane(mi_, 48);     \
            unsigned ra_ = r0_ > r1_ ? r0_ : r1_;                            \
            unsigned rb_ = r2_ > r3_ ? r2_ : r3_;                            \
            unsigned mx_ = ra_ > rb_ ? ra_ : rb_;                            \
            int e_  = (int)((mx_ >> 23) & 0xFF);                             \
            int Me_ = 284 - e_;                                              \
            Me_ = Me_ < 1 ? 1 : (Me_ > 254 ? 254 : Me_);                     \
            MB_ = __builtin_bit_cast(float, Me_ << 23);                      \
            S2y += Me_ - 127;                                                \
        }                                                                    \
        f32x2 M2_; M2_.x = MA_; M2_.y = MB_;                                 \
        prev2 = prev2 * M2_;                                                 \
        dgp2  = dgp2  * M2_;                                                 \
        cap2  = cap2  * M2_;                                                 \
    } while (0)

    // chunk: prefetch next 32, run 32 steps, renorm
#define CHUNKRUN(CBASE, CUR, NXT, CAPF) do {                                 \
        _Pragma("unroll")                                                    \
        for (int k = 0; k < 32; ++k) NXT[k] = xp[(CBASE) + 32 + k];          \
        __builtin_amdgcn_sched_barrier(0);                                   \
        _Pragma("unroll")                                                    \
        for (int k = 0; k < 32; ++k) STEP(CUR[k], (CBASE) + k, CAPF);        \
        RENORM();                                                            \
        __builtin_amdgcn_sched_barrier(0);                                   \
    } while (0)

    CHUNKRUN(  0, A,  Bv, 0);
    CHUNKRUN( 32, Bv, A,  0);
    CHUNKRUN( 64, A,  Bv, 0);
    CHUNKRUN( 96, Bv, A,  0);
    CHUNKRUN(128, A,  Bv, 0);
    CHUNKRUN(160, Bv, A,  0);
    CHUNKRUN(192, A,  Bv, 0);
    CHUNKRUN(224, Bv, A,  1);    // step 255: lane 0 captures
    CHUNKRUN(256, A,  Bv, 1);    // steps 256..287: lanes 1..32
    // tail: steps 288..318 (31 steps), lanes 33..63 capture, no renorm
#pragma unroll
    for (int k = 0; k < 31; ++k) STEP(Bv[k], 288 + k, 1);

    // ---- epilogue: rescale caps to ~2^0, mirror bwd, combine, reduce ----
    {
        float MA_, MB_;
        {
            float m_ = cap2.x;
            m_ = fmaxf(m_, row_ror<8>(m_));
            m_ = fmaxf(m_, row_ror<4>(m_));
            m_ = fmaxf(m_, row_ror<2>(m_));
            m_ = fmaxf(m_, row_ror<1>(m_));
            int mi_ = __builtin_bit_cast(int, m_);
            unsigned r0_ = (unsigned)__builtin_amdgcn_readlane(mi_, 0);
            unsigned r1_ = (unsigned)__builtin_amdgcn_readlane(mi_, 16);
            unsigned r2_ = (unsigned)__builtin_amdgcn_readlane(mi_, 32);
            unsigned r3_ = (unsigned)__builtin_amdgcn_readlane(mi_, 48);
            unsigned ra_ = r0_ > r1_ ? r0_ : r1_;
            unsigned rb_ = r2_ > r3_ ? r2_ : r3_;
            unsigned mx_ = ra_ > rb_ ? ra_ : rb_;
            int e_  = (int)((mx_ >> 23) & 0xFF);
            int Me_ = 254 - e_;                    // target ~2^0
            Me_ = Me_ < 1 ? 1 : (Me_ > 254 ? 254 : Me_);
            MA_ = __builtin_bit_cast(float, Me_ << 23);
            S2x += Me_ - 127;
        }
        {
            float m_ = cap2.y;
            m_ = fmaxf(m_, row_ror<8>(m_));
            m_ = fmaxf(m_, row_ror<4>(m_));
            m_ = fmaxf(m_, row_ror<2>(m_));
            m_ = fmaxf(m_, row_ror<1>(m_));
            int mi_ = __builtin_bit_cast(int, m_);
            unsigned r0_ = (unsigned)__builtin_amdgcn_readlane(mi_, 0);
            unsigned r1_ = (unsigned)__builtin_amdgcn_readlane(mi_, 16);
            unsigned r2_ = (unsigned)__builtin_amdgcn_readlane(mi_, 32);
            unsigned r3_ = (unsigned)__builtin_amdgcn_readlane(mi_, 48);
            unsigned ra_ = r0_ > r1_ ? r0_ : r1_;
            unsigned rb_ = r2_ > r3_ ? r2_ : r3_;
            unsigned mx_ = ra_ > rb_ ? ra_ : rb_;
            int e_  = (int)((mx_ >> 23) & 0xFF);
            int Me_ = 254 - e_;
            Me_ = Me_ < 1 ? 1 : (Me_ > 254 ? 254 : Me_);
            MB_ = __builtin_bit_cast(float, Me_ << 23);
            S2y += Me_ - 127;
        }
        f32x2 M2_; M2_.x = MA_; M2_.y = MB_;
        cap2 = cap2 * M2_;
    }
    // lane j needs Zb(256, j) and Zb(256, j+1); bwd column j lives at lane 63-j
    float cbj  = __shfl(cap2.y, 63 - lane);
    float cbj1 = __shfl(cap2.y, 62 - lane);   // lane63 garbage; capf(63)=0
    float s = cap2.x * (cbj + cbj1);
    // rotation all-reduce sum within 16-rows, then combine 4 groups
    float m = s;
    m += row_ror<8>(m);
    m += row_ror<4>(m);
    m += row_ror<2>(m);
    m += row_ror<1>(m);
    int mi = __builtin_bit_cast(int, m);
    float tot = m;                                       // lanes 48..63 group
    tot += __builtin_bit_cast(float, __builtin_amdgcn_readlane(mi, 0));
    tot += __builtin_bit_cast(float, __builtin_amdgcn_readlane(mi, 16));
    tot += __builtin_bit_cast(float, __builtin_amdgcn_readlane(mi, 32));

    if (lane == 63) {
        float D = ((float)(S2x + S2y) - log2f(tot)) * LN2;
        out[b * NFILT + f] = D * (1.0f / (float)T_LEN);
    }
#undef STEP
#undef RENORM
#undef CHUNKRUN
}

extern "C" void kernel_launch(void* const* d_in, const int* in_sizes, int n_in,
                              void* d_out, int out_size, void* d_ws, size_t ws_size,
                              hipStream_t stream) {
    const float* x      = (const float*)d_in[0];
    const float* protos = (const float*)d_in[1];
    float* out          = (float*)d_out;

    dim3 grid(512);    // 512 blocks x 4 waves = 2048 waves = 2 waves/SIMD
    dim3 block(256);   // one (b,f) problem per wave, fwd+bwd packed
    hipLaunchKernelGGL(dtw_kernel, grid, block, 0, stream, x, protos, out);
}